// Round 4
// baseline (454.064 us; speedup 1.0000x reference)
//
#include <hip/hip_runtime.h>
#include <hip/hip_bf16.h>

#define N_NODES 50000
#define N_EDGES 800000
#define NF 64            // IN_F == OUT_F == 64
#define BUCK_SHIFT 6
#define BUCK_SIZE 64     // rows per bucket
#define NBUK ((N_NODES + BUCK_SIZE - 1) / BUCK_SIZE)  // 782
#define CAP 1536         // edges per bucket region (mean 1024, sd 32 -> +16 sigma)
#define CHUNK 4096       // edges per bin_scatter block

// -------------------- kernel 1: support = bf16(x @ W) --------------------
// One wave per row; lane f holds W[:,f] in 64 VGPRs. x-row reads are
// wave-uniform (readfirstlane) -> scalar loads broadcast into FMAs.
__global__ __launch_bounds__(256) void gemm_xw(
    const float* __restrict__ x, const float* __restrict__ w,
    __hip_bfloat16* __restrict__ support) {
  const int lane = threadIdx.x & 63;
  const int wave = threadIdx.x >> 6;

  float wcol[NF];
#pragma unroll
  for (int k = 0; k < NF; ++k) wcol[k] = w[k * NF + lane];

  const int nwaves = gridDim.x * 4;
  for (int row = blockIdx.x * 4 + wave; row < N_NODES; row += nwaves) {
    const int row_u = __builtin_amdgcn_readfirstlane(row);
    const float* xr = x + (size_t)row_u * NF;
    float a0 = 0.f, a1 = 0.f, a2 = 0.f, a3 = 0.f;
#pragma unroll
    for (int k = 0; k < NF; k += 4) {
      a0 = fmaf(xr[k + 0], wcol[k + 0], a0);
      a1 = fmaf(xr[k + 1], wcol[k + 1], a1);
      a2 = fmaf(xr[k + 2], wcol[k + 2], a2);
      a3 = fmaf(xr[k + 3], wcol[k + 3], a3);
    }
    support[(size_t)row_u * NF + lane] = __float2bfloat16((a0 + a1) + (a2 + a3));
  }
}

// -------------------- kernel 2: bin edges into fixed-capacity buckets ------
// Block = 4096 contiguous edges. LDS histogram over 782 buckets; one global
// atomic per (block,bucket) reserves a contiguous run inside the bucket's
// fixed CAP region; edges written in ~5-edge runs (line-merged in L2).
// meta: local row (6b) in bits 16.., col (<50000 < 2^16) in low 16 bits.
__global__ __launch_bounds__(256) void bin_scatter(
    const int* __restrict__ erow, const int* __restrict__ ecol,
    const float* __restrict__ eval, int* __restrict__ cursor,
    int2* __restrict__ stage1) {
  __shared__ int hist[NBUK];
  __shared__ int base[NBUK];
  __shared__ int lcur[NBUK];
  for (int t = threadIdx.x; t < NBUK; t += 256) hist[t] = 0;
  __syncthreads();

  const int e0 = blockIdx.x * CHUNK;
  const int e1 = min(e0 + CHUNK, N_EDGES);
  for (int e = e0 + threadIdx.x; e < e1; e += 256)
    atomicAdd(&hist[erow[e] >> BUCK_SHIFT], 1);
  __syncthreads();

  for (int t = threadIdx.x; t < NBUK; t += 256) {
    const int c = hist[t];
    base[t] = c ? t * CAP + atomicAdd(&cursor[t], c) : 0;
    lcur[t] = 0;
  }
  __syncthreads();

  for (int e = e0 + threadIdx.x; e < e1; e += 256) {
    const int r = erow[e];
    const int b = r >> BUCK_SHIFT;
    const int ofs = atomicAdd(&lcur[b], 1);
    const int pos = base[b] + ofs;
    if (pos < (b + 1) * CAP)  // safety clamp; statistically never taken
      stage1[pos] = make_int2(((r & (BUCK_SIZE - 1)) << 16) | ecol[e],
                              __float_as_int(eval[e]));
  }
}

// -------------------- kernel 3: fused bucket SpMM + bias --------------------
// One block per 64-row bucket. LDS tile[64][64] f32 initialized with bias;
// each wave walks a contiguous quarter of the bucket's edges, gathers the
// bf16 support row (128 B coalesced) and ds_add_f32's v*s into the tile
// (stride-1 lanes -> conflict-free). Single coalesced float4 writeback.
__global__ __launch_bounds__(256) void spmm_bucket(
    const __hip_bfloat16* __restrict__ support, const int* __restrict__ cursor,
    const int2* __restrict__ stage1, const float* __restrict__ bias,
    float* __restrict__ out) {
  __shared__ float tile[BUCK_SIZE * NF];  // 16 KB
  const int b = blockIdx.x;
  const int tid = threadIdx.x;
  const int lane = tid & 63;
  const int wave = tid >> 6;

  const float bv = bias[lane];
  for (int i = tid; i < BUCK_SIZE * NF; i += 256) tile[i] = bv;  // i%64==lane%64
  __syncthreads();

  int cnt = cursor[b];
  cnt = cnt > CAP ? CAP : cnt;
  const int2* eb = stage1 + (size_t)b * CAP;

  // contiguous per-wave range (imbalance absorbed by the end barrier)
  const int wlen = (cnt + 3) >> 2;
  const int i0 = __builtin_amdgcn_readfirstlane(wave * wlen);
  const int i1 = __builtin_amdgcn_readfirstlane(min(i0 + wlen, cnt));

  int i = i0;
  for (; i + 4 <= i1; i += 4) {
    const int2 m0 = eb[i + 0];
    const int2 m1 = eb[i + 1];
    const int2 m2 = eb[i + 2];
    const int2 m3 = eb[i + 3];
    const float s0 = __bfloat162float(support[(size_t)(m0.x & 0xFFFF) * NF + lane]);
    const float s1 = __bfloat162float(support[(size_t)(m1.x & 0xFFFF) * NF + lane]);
    const float s2 = __bfloat162float(support[(size_t)(m2.x & 0xFFFF) * NF + lane]);
    const float s3 = __bfloat162float(support[(size_t)(m3.x & 0xFFFF) * NF + lane]);
    atomicAdd(&tile[(m0.x >> 16) * NF + lane], __int_as_float(m0.y) * s0);
    atomicAdd(&tile[(m1.x >> 16) * NF + lane], __int_as_float(m1.y) * s1);
    atomicAdd(&tile[(m2.x >> 16) * NF + lane], __int_as_float(m2.y) * s2);
    atomicAdd(&tile[(m3.x >> 16) * NF + lane], __int_as_float(m3.y) * s3);
  }
  for (; i < i1; ++i) {
    const int2 m0 = eb[i];
    const float s0 = __bfloat162float(support[(size_t)(m0.x & 0xFFFF) * NF + lane]);
    atomicAdd(&tile[(m0.x >> 16) * NF + lane], __int_as_float(m0.y) * s0);
  }
  __syncthreads();

  const int row0 = b << BUCK_SHIFT;
  const int lim = min(BUCK_SIZE, N_NODES - row0) * (NF / 4);  // valid float4s
  float4* o4 = reinterpret_cast<float4*>(out + (size_t)row0 * NF);
  const float4* t4 = reinterpret_cast<const float4*>(tile);
  for (int j = tid; j < lim; j += 256) o4[j] = t4[j];
}

// -------------------- launch --------------------
extern "C" void kernel_launch(void* const* d_in, const int* in_sizes, int n_in,
                              void* d_out, int out_size, void* d_ws,
                              size_t ws_size, hipStream_t stream) {
  const float* x = (const float*)d_in[0];
  const int* erow = (const int*)d_in[1];
  const int* ecol = (const int*)d_in[2];
  const float* eval = (const float*)d_in[3];
  const float* w = (const float*)d_in[4];
  const float* bias = (const float*)d_in[5];
  float* out = (float*)d_out;

  // workspace layout (16B-aligned)
  char* ws = (char*)d_ws;
  __hip_bfloat16* support = (__hip_bfloat16*)(ws);  //  6,400,000 B
  int2* stage1 = (int2*)(ws + 6400000);             //  9,609,216 B (782*1536*8)
  int* cursor = (int*)(ws + 16009216);              //      3,128 B (782)
  // total ~16.0 MB

  hipMemsetAsync(cursor, 0, NBUK * sizeof(int), stream);

  gemm_xw<<<1024, 256, 0, stream>>>(x, w, support);
  bin_scatter<<<(N_EDGES + CHUNK - 1) / CHUNK, 256, 0, stream>>>(
      erow, ecol, eval, cursor, stage1);
  spmm_bucket<<<NBUK, 256, 0, stream>>>(support, cursor, stage1, bias, out);
}

// Round 5
// 139.119 us; speedup vs baseline: 3.2639x; 3.2639x over previous
//
#include <hip/hip_runtime.h>
#include <hip/hip_bf16.h>

#define N_NODES 50000
#define N_EDGES 800000
#define NF 64            // IN_F == OUT_F == 64
#define BUCK_SHIFT 5
#define BUCK_SIZE 32     // rows per bucket
#define NBUK ((N_NODES + BUCK_SIZE - 1) / BUCK_SIZE)  // 1563
#define CAP 768          // slots per bucket (mean 512, sd ~23 -> +11 sigma)
#define CHUNK 4096       // edges per bin_scatter block

// -------------------- kernel 1: support = bf16(x @ W) --------------------
// One wave per row; lane f holds W[:,f] in 64 VGPRs. x-row reads are
// wave-uniform (readfirstlane) -> scalar loads broadcast into FMAs.
__global__ __launch_bounds__(256) void gemm_xw(
    const float* __restrict__ x, const float* __restrict__ w,
    __hip_bfloat16* __restrict__ support) {
  const int lane = threadIdx.x & 63;
  const int wave = threadIdx.x >> 6;

  float wcol[NF];
#pragma unroll
  for (int k = 0; k < NF; ++k) wcol[k] = w[k * NF + lane];

  const int nwaves = gridDim.x * 4;
  for (int row = blockIdx.x * 4 + wave; row < N_NODES; row += nwaves) {
    const int row_u = __builtin_amdgcn_readfirstlane(row);
    const float* xr = x + (size_t)row_u * NF;
    float a0 = 0.f, a1 = 0.f, a2 = 0.f, a3 = 0.f;
#pragma unroll
    for (int k = 0; k < NF; k += 4) {
      a0 = fmaf(xr[k + 0], wcol[k + 0], a0);
      a1 = fmaf(xr[k + 1], wcol[k + 1], a1);
      a2 = fmaf(xr[k + 2], wcol[k + 2], a2);
      a3 = fmaf(xr[k + 3], wcol[k + 3], a3);
    }
    support[(size_t)row_u * NF + lane] = __float2bfloat16((a0 + a1) + (a2 + a3));
  }
}

// -------------------- kernel 2: bin edges into fixed-capacity buckets ------
// Block = 4096 contiguous edges. LDS histogram over 1563 buckets; one global
// atomic per (block,bucket) reserves a contiguous run inside the bucket's
// fixed CAP region. meta: local row (5b) in bits 16.., col (<2^16) low.
__global__ __launch_bounds__(256) void bin_scatter(
    const int* __restrict__ erow, const int* __restrict__ ecol,
    const float* __restrict__ eval, int* __restrict__ cursor,
    int2* __restrict__ stage1) {
  __shared__ int hist[NBUK];
  __shared__ int base[NBUK];
  __shared__ int lcur[NBUK];
  for (int t = threadIdx.x; t < NBUK; t += 256) hist[t] = 0;
  __syncthreads();

  const int e0 = blockIdx.x * CHUNK;
  const int e1 = min(e0 + CHUNK, N_EDGES);
  for (int e = e0 + threadIdx.x; e < e1; e += 256)
    atomicAdd(&hist[erow[e] >> BUCK_SHIFT], 1);
  __syncthreads();

  for (int t = threadIdx.x; t < NBUK; t += 256) {
    const int c = hist[t];
    base[t] = c ? t * CAP + atomicAdd(&cursor[t], c) : 0;
    lcur[t] = 0;
  }
  __syncthreads();

  for (int e = e0 + threadIdx.x; e < e1; e += 256) {
    const int r = erow[e];
    const int b = r >> BUCK_SHIFT;
    const int ofs = atomicAdd(&lcur[b], 1);
    const int pos = base[b] + ofs;
    if (pos < (b + 1) * CAP)  // safety clamp; statistically never taken
      stage1[pos] = make_int2(((r & (BUCK_SIZE - 1)) << 16) | ecol[e],
                              __float_as_int(eval[e]));
  }
}

// -------------------- kernel 3: fused sort-in-LDS + register SpMM ----------
// One block per 32-row bucket. Phase A: load bucket edges into LDS, count
// per-row (int LDS atomics), 32-wide shfl scan, place a row-sorted copy in
// LDS. Phase B: each wave register-accumulates 8 rows (lane = feature),
// x4-unrolled coalesced bf16 gathers, one coalesced store per row. No f32
// atomics anywhere; 1563 blocks / 6252 waves for latency hiding.
__global__ __launch_bounds__(256) void spmm_sorted(
    const __hip_bfloat16* __restrict__ support, const int* __restrict__ cursor,
    const int2* __restrict__ stage1, const float* __restrict__ bias,
    float* __restrict__ out) {
  __shared__ int2 raw[CAP];             // 6 KB
  __shared__ int2 srt[CAP];             // 6 KB
  __shared__ int rcnt[BUCK_SIZE];
  __shared__ int rofs[BUCK_SIZE];
  __shared__ int rcur[BUCK_SIZE];
  const int b = blockIdx.x;
  const int tid = threadIdx.x;
  const int lane = tid & 63;
  const int wave = tid >> 6;

  if (tid < BUCK_SIZE) rcnt[tid] = 0;
  __syncthreads();

  int cnt = cursor[b];
  cnt = cnt > CAP ? CAP : cnt;
  const int2* eb = stage1 + (size_t)b * CAP;

  // Phase A1: load + per-row count
  for (int i = tid; i < cnt; i += 256) {
    const int2 m = eb[i];
    raw[i] = m;
    atomicAdd(&rcnt[m.x >> 16], 1);
  }
  __syncthreads();

  // Phase A2: exclusive scan of 32 counters (wave 0)
  if (tid < 64) {
    const int v = (lane < BUCK_SIZE) ? rcnt[lane] : 0;
    int sc = v;
#pragma unroll
    for (int off = 1; off < 32; off <<= 1) {
      const int up = __shfl_up(sc, off, 64);
      if (lane >= off) sc += up;
    }
    if (lane < BUCK_SIZE) {
      rofs[lane] = sc - v;
      rcur[lane] = sc - v;
    }
  }
  __syncthreads();

  // Phase A3: place row-sorted
  for (int i = tid; i < cnt; i += 256) {
    const int2 m = raw[i];
    const int p = atomicAdd(&rcur[m.x >> 16], 1);
    srt[p] = m;
  }
  __syncthreads();

  // Phase B: per-row register accumulation, 8 rows per wave
  const int row0 = b << BUCK_SHIFT;
  const float bv = bias[lane];
#pragma unroll
  for (int rr = 0; rr < 8; ++rr) {
    const int rl = wave * 8 + rr;
    const int row = row0 + rl;
    if (row >= N_NODES) break;  // wave-uniform
    const int s = __builtin_amdgcn_readfirstlane(rofs[rl]);
    const int e = __builtin_amdgcn_readfirstlane(rofs[rl] + rcnt[rl]);
    float a0 = 0.f, a1 = 0.f, a2 = 0.f, a3 = 0.f;
    int i = s;
    for (; i + 4 <= e; i += 4) {
      const int2 m0 = srt[i + 0];
      const int2 m1 = srt[i + 1];
      const int2 m2 = srt[i + 2];
      const int2 m3 = srt[i + 3];
      const float s0 = __bfloat162float(support[(size_t)(m0.x & 0xFFFF) * NF + lane]);
      const float s1 = __bfloat162float(support[(size_t)(m1.x & 0xFFFF) * NF + lane]);
      const float s2 = __bfloat162float(support[(size_t)(m2.x & 0xFFFF) * NF + lane]);
      const float s3 = __bfloat162float(support[(size_t)(m3.x & 0xFFFF) * NF + lane]);
      a0 = fmaf(__int_as_float(m0.y), s0, a0);
      a1 = fmaf(__int_as_float(m1.y), s1, a1);
      a2 = fmaf(__int_as_float(m2.y), s2, a2);
      a3 = fmaf(__int_as_float(m3.y), s3, a3);
    }
    for (; i < e; ++i) {
      const int2 m0 = srt[i];
      a0 = fmaf(__int_as_float(m0.y),
                __bfloat162float(support[(size_t)(m0.x & 0xFFFF) * NF + lane]),
                a0);
    }
    out[(size_t)row * NF + lane] = ((a0 + a1) + (a2 + a3)) + bv;
  }
}

// -------------------- launch --------------------
extern "C" void kernel_launch(void* const* d_in, const int* in_sizes, int n_in,
                              void* d_out, int out_size, void* d_ws,
                              size_t ws_size, hipStream_t stream) {
  const float* x = (const float*)d_in[0];
  const int* erow = (const int*)d_in[1];
  const int* ecol = (const int*)d_in[2];
  const float* eval = (const float*)d_in[3];
  const float* w = (const float*)d_in[4];
  const float* bias = (const float*)d_in[5];
  float* out = (float*)d_out;

  // workspace layout (16B-aligned)
  char* ws = (char*)d_ws;
  __hip_bfloat16* support = (__hip_bfloat16*)(ws);  //  6,400,000 B
  int2* stage1 = (int2*)(ws + 6400000);             //  9,603,072 B (1563*768*8)
  int* cursor = (int*)(ws + 16003072);              //      6,252 B (1563)
  // total ~16.0 MB

  hipMemsetAsync(cursor, 0, NBUK * sizeof(int), stream);

  gemm_xw<<<1024, 256, 0, stream>>>(x, w, support);
  bin_scatter<<<(N_EDGES + CHUNK - 1) / CHUNK, 256, 0, stream>>>(
      erow, ecol, eval, cursor, stage1);
  spmm_sorted<<<NBUK, 256, 0, stream>>>(support, cursor, stage1, bias, out);
}